// Round 3
// baseline (434.642 us; speedup 1.0000x reference)
//
#include <hip/hip_runtime.h>
#include <cstdint>
#include <cstddef>

// Problem dims (B, D, F, T, H) = (256, 128, 8, 128, 128)
#define Bn 256
#define Dn 128
#define Fn 8
#define Tn 128
#define Hn 128
#define Kn 1024   // D*F
#define Mn 512    // 4*H

typedef float f32x4 __attribute__((ext_vector_type(4)));
typedef short s16x8 __attribute__((ext_vector_type(8)));
typedef _Float16 h16x2 __attribute__((ext_vector_type(2)));

#if defined(__has_builtin)
#if __has_builtin(__builtin_amdgcn_fdot2)
#define HAVE_FDOT2 1
#else
#define HAVE_FDOT2 0
#endif
#else
#define HAVE_FDOT2 0
#endif

__device__ __forceinline__ unsigned short f32_to_bf16_rne(float f) {
  union { float f; uint32_t u; } v; v.f = f;
  uint32_t u = v.u;
  u += 0x7fffu + ((u >> 16) & 1u);
  return (unsigned short)(u >> 16);
}
__device__ __forceinline__ float sigm(float x) { return 1.0f / (1.0f + __expf(-x)); }
__device__ __forceinline__ float tanh_fast(float x) { return 1.0f - 2.0f / (__expf(2.0f * x) + 1.0f); }

// ---------------------------------------------------------------------------
// K1: ex[b,d] = input[b,d,:,:] . w_x   (one wave per (b,d))
// softmax shift-invariance kills the h/c/b_attn term entirely.
// ---------------------------------------------------------------------------
__global__ __launch_bounds__(256) void k_ex(const float* __restrict__ input,
                                            const float* __restrict__ w_attn,
                                            float* __restrict__ ex) {
  __shared__ float wx[Kn];
  const int tid = threadIdx.x;
  ((float4*)wx)[tid] = ((const float4*)(w_attn + 2 * Hn))[tid];
  __syncthreads();
  const int w = tid >> 6, lane = tid & 63;
  const int gid = blockIdx.x * 4 + w;  // b*128 + d
  const float4* xp = (const float4*)(input + (size_t)gid * Kn);
  const float4* wx4 = (const float4*)wx;
  float acc = 0.f;
#pragma unroll
  for (int r = 0; r < 4; ++r) {
    float4 x = xp[lane + r * 64];
    float4 ww = wx4[lane + r * 64];
    acc += x.x * ww.x + x.y * ww.y + x.z * ww.z + x.w * ww.w;
  }
#pragma unroll
  for (int off = 32; off; off >>= 1) acc += __shfl_xor(acc, off);
  if (lane == 0) ex[gid] = acc;
}

// ---------------------------------------------------------------------------
// K2: W_ih (512x1024 f32) -> hi/lo bf16 pair, pre-swizzled into MFMA A-frag
// dst[((mt*32+kt)*64+lane)*8 + j] = W[mt*16+(lane&15)][kt*32+(lane>>4)*8+j]
// ---------------------------------------------------------------------------
__global__ __launch_bounds__(256) void k_prep_wih(const float* __restrict__ W_ih,
                                                  unsigned short* __restrict__ whi,
                                                  unsigned short* __restrict__ wlo) {
  const int gid = blockIdx.x * 256 + threadIdx.x;  // 65536 groups of 8
  const int lane = gid & 63;
  const int kt = (gid >> 6) & 31;
  const int mt = gid >> 11;
  const int row = mt * 16 + (lane & 15);
  const int col = kt * 32 + (lane >> 4) * 8;
  const float* src = W_ih + row * Kn + col;
  unsigned short hi8[8], lo8[8];
#pragma unroll
  for (int j = 0; j < 8; ++j) {
    float wv = src[j];
    unsigned short h = f32_to_bf16_rne(wv);
    hi8[j] = h;
    union { uint32_t u; float f; } hb; hb.u = ((uint32_t)h) << 16;
    lo8[j] = f32_to_bf16_rne(wv - hb.f);
  }
  uint4 ph, pl;
  ph.x = (uint32_t)hi8[0] | ((uint32_t)hi8[1] << 16);
  ph.y = (uint32_t)hi8[2] | ((uint32_t)hi8[3] << 16);
  ph.z = (uint32_t)hi8[4] | ((uint32_t)hi8[5] << 16);
  ph.w = (uint32_t)hi8[6] | ((uint32_t)hi8[7] << 16);
  pl.x = (uint32_t)lo8[0] | ((uint32_t)lo8[1] << 16);
  pl.y = (uint32_t)lo8[2] | ((uint32_t)lo8[3] << 16);
  pl.z = (uint32_t)lo8[4] | ((uint32_t)lo8[5] << 16);
  pl.w = (uint32_t)lo8[6] | ((uint32_t)lo8[7] << 16);
  ((uint4*)whi)[gid] = ph;
  ((uint4*)wlo)[gid] = pl;
}

// ---------------------------------------------------------------------------
// K3: W_hh (512x128 f32) -> packed f16 pairs, transposed: whhp[kk*512+j] =
// (f16(W[j][2kk]), f16(W[j][2kk+1]))  => k_rec loads are fully coalesced.
// ---------------------------------------------------------------------------
__global__ __launch_bounds__(256) void k_prep_whh(const float* __restrict__ W_hh,
                                                  uint32_t* __restrict__ whhp) {
  const int g = blockIdx.x * 256 + threadIdx.x;  // 32768
  const int j = g & 511, kk = g >> 9;
  float2 wv = ((const float2*)(W_hh + (size_t)j * Hn))[kk];
  h16x2 t2; t2.x = (_Float16)wv.x; t2.y = (_Float16)wv.y;
  union { h16x2 h; uint32_t u; } cv; cv.h = t2;
  whhp[kk * 512 + j] = cv.u;
}

// ---------------------------------------------------------------------------
// K4: gates GEMM. grid = 1024 blocks: (b = bid>>2, panel p = bid&3), 256 thr.
// Per block: rows j in [p*128, p*128+128), all 128 t, K=1024. Double-buffered
// LDS staging, prefetch next K-tile into regs during MFMA, 1 barrier/kt.
// Output: gx[b][j][t] f16 via LDS-bounce coalesced stores.
// ---------------------------------------------------------------------------
__global__ __launch_bounds__(256, 3) void k_gates(
    const float* __restrict__ input, const float* __restrict__ ex,
    const unsigned short* __restrict__ whi, const unsigned short* __restrict__ wlo,
    unsigned short* __restrict__ gx) {
  // smem union: [ staging buf0 16KB | buf1 16KB ]  vs  [ bounce 128x136 f16 = 34816B ]
  __shared__ __align__(16) unsigned char smem[34816];
  __shared__ float a_lds[Dn];
  __shared__ float sred[8];
  unsigned short* buf0 = (unsigned short*)smem;
  unsigned short* buf1 = buf0 + 8192;
  _Float16* lds_out = (_Float16*)smem;

  const int tid = threadIdx.x;
  const int b = blockIdx.x >> 2;
  const int p = blockIdx.x & 3;
  const int w = tid >> 6;
  const int lane = tid & 63;
  const int quad = lane >> 4;
  const int l15 = lane & 15;

  // ---- in-block softmax over ex[b,:] -> a_lds ----
  float v = (tid < Dn) ? ex[b * Dn + tid] : -3.4e38f;
  float m = v;
#pragma unroll
  for (int off = 32; off; off >>= 1) m = fmaxf(m, __shfl_xor(m, off));
  if (lane == 0) sred[w] = m;
  __syncthreads();
  m = fmaxf(fmaxf(sred[0], sred[1]), fmaxf(sred[2], sred[3]));
  float e = (tid < Dn) ? __expf(v - m) : 0.f;
  float s = e;
#pragma unroll
  for (int off = 32; off; off >>= 1) s += __shfl_xor(s, off);
  if (lane == 0) sred[4 + w] = s;
  __syncthreads();
  s = sred[4] + sred[5] + sred[6] + sred[7];
  if (tid < Dn) a_lds[tid] = e / s;

  f32x4 acc[2][8];
#pragma unroll
  for (int i = 0; i < 2; ++i)
#pragma unroll
    for (int j = 0; j < 8; ++j) { f32x4 z = {0.f, 0.f, 0.f, 0.f}; acc[i][j] = z; }

  const int kb = tid >> 5;         // 0..7 (k-group of 8 within 64-tile)
  const int t0 = (tid & 31) * 4;   // 0..124
  const float* xb = input + (size_t)b * Kn * Tn;

  __syncthreads();  // a_lds ready

  // ---- initial stage of tile 0 ----
  {
    float4 xr[8];
    const float* src = xb + (size_t)(kb * 8) * Tn + t0;
#pragma unroll
    for (int j = 0; j < 8; ++j) xr[j] = *(const float4*)(src + (size_t)j * Tn);
    const float av = a_lds[kb];
#pragma unroll
    for (int i = 0; i < 4; ++i) {
      unsigned short hx[8];
#pragma unroll
      for (int j = 0; j < 8; ++j) hx[j] = f32_to_bf16_rne(av * ((const float*)&xr[j])[i]);
      uint4 pk;
      pk.x = (uint32_t)hx[0] | ((uint32_t)hx[1] << 16);
      pk.y = (uint32_t)hx[2] | ((uint32_t)hx[3] << 16);
      pk.z = (uint32_t)hx[4] | ((uint32_t)hx[5] << 16);
      pk.w = (uint32_t)hx[6] | ((uint32_t)hx[7] << 16);
      const int tsw = (t0 + i) ^ ((kb & 1) << 2);  // bank spread
      *(uint4*)(buf0 + (size_t)(kb * 128 + tsw) * 8) = pk;
    }
  }
  __syncthreads();

  for (int kt = 0; kt < 16; ++kt) {
    unsigned short* cur = (kt & 1) ? buf1 : buf0;
    unsigned short* nxt = (kt & 1) ? buf0 : buf1;
    // ---- prefetch next tile into regs (no dependency on MFMA below) ----
    float4 xr[8];
    if (kt < 15) {
      const float* src = xb + (size_t)((kt + 1) * 64 + kb * 8) * Tn + t0;
#pragma unroll
      for (int j = 0; j < 8; ++j) xr[j] = *(const float4*)(src + (size_t)j * Tn);
    }
    // ---- MFMA on current tile ----
#pragma unroll
    for (int kf = 0; kf < 2; ++kf) {
      const int ktg = kt * 2 + kf;
      s16x8 afh[2], afl[2];
#pragma unroll
      for (int mt = 0; mt < 2; ++mt) {
        const int mtg = p * 8 + w * 2 + mt;
        const size_t fo = ((size_t)(mtg * 32 + ktg) * 64 + lane) * 8;
        afh[mt] = *(const s16x8*)(whi + fo);
        afl[mt] = *(const s16x8*)(wlo + fo);
      }
      s16x8 bfr[8];
      const int kbr = kf * 4 + quad;
#pragma unroll
      for (int nt = 0; nt < 8; ++nt) {
        const int tsw = (nt * 16 + l15) ^ ((kbr & 1) << 2);
        bfr[nt] = *(const s16x8*)(cur + (size_t)(kbr * 128 + tsw) * 8);
      }
#pragma unroll
      for (int mt = 0; mt < 2; ++mt)
#pragma unroll
        for (int nt = 0; nt < 8; ++nt) {
          acc[mt][nt] = __builtin_amdgcn_mfma_f32_16x16x32_bf16(afh[mt], bfr[nt], acc[mt][nt], 0, 0, 0);
          acc[mt][nt] = __builtin_amdgcn_mfma_f32_16x16x32_bf16(afl[mt], bfr[nt], acc[mt][nt], 0, 0, 0);
        }
    }
    // ---- convert prefetched tile and store into other buffer ----
    if (kt < 15) {
      const float av = a_lds[(kt + 1) * 8 + kb];
#pragma unroll
      for (int i = 0; i < 4; ++i) {
        unsigned short hx[8];
#pragma unroll
        for (int j = 0; j < 8; ++j) hx[j] = f32_to_bf16_rne(av * ((const float*)&xr[j])[i]);
        uint4 pk;
        pk.x = (uint32_t)hx[0] | ((uint32_t)hx[1] << 16);
        pk.y = (uint32_t)hx[2] | ((uint32_t)hx[3] << 16);
        pk.z = (uint32_t)hx[4] | ((uint32_t)hx[5] << 16);
        pk.w = (uint32_t)hx[6] | ((uint32_t)hx[7] << 16);
        const int tsw = (t0 + i) ^ ((kb & 1) << 2);
        *(uint4*)(nxt + (size_t)(kb * 128 + tsw) * 8) = pk;
      }
    }
    __syncthreads();
  }

  // ---- epilogue: acc -> LDS bounce (pitch 136) -> coalesced global f16 ----
#pragma unroll
  for (int mt = 0; mt < 2; ++mt)
#pragma unroll
    for (int nt = 0; nt < 8; ++nt)
#pragma unroll
      for (int r = 0; r < 4; ++r) {
        const int jl = (w * 2 + mt) * 16 + quad * 4 + r;  // 0..127
        lds_out[jl * 136 + nt * 16 + l15] = (_Float16)acc[mt][nt][r];
      }
  __syncthreads();
  {
    const int jr = tid >> 1, half = tid & 1;
    const uint4* lsrc = (const uint4*)(lds_out + jr * 136 + half * 64);
    uint4* gdst = (uint4*)(gx + ((size_t)(b * Mn + p * 128 + jr)) * Tn + half * 64);
#pragma unroll
    for (int i = 0; i < 8; ++i) gdst[i] = lsrc[i];
  }
}

// ---------------------------------------------------------------------------
// K5: LSTM recurrence. 256 blocks (1/batch) x 512 thr. gx[b] (128KB f16)
// preloaded into LDS (pitch 132 to spread banks); W_hh row in VGPRs (f16
// pairs); fdot2 matvec; activation replicated across all waves.
// ---------------------------------------------------------------------------
__global__ __launch_bounds__(512) void k_rec(
    const unsigned short* __restrict__ gx, const uint32_t* __restrict__ whhp,
    const float* __restrict__ b_ih, const float* __restrict__ b_hh,
    float* __restrict__ out) {
  __shared__ __align__(16) unsigned short gxl[512 * 132];  // 135168 B
  __shared__ float gstep[Mn];
  __shared__ __align__(4) _Float16 h2l[Hn];
  __shared__ float h32[Hn];

  const int tid = threadIdx.x;
  const int b = blockIdx.x;

  // ---- preload gx[b] into LDS: thread (seg,rr) covers 32 elems per row ----
  {
    const int seg = tid & 3, rr = tid >> 2;
#pragma unroll
    for (int it = 0; it < 4; ++it) {
      const int row = it * 128 + rr;
      const uint4* gsrc = (const uint4*)(gx + ((size_t)b * Mn + row) * Tn + seg * 32);
      uint2* dst = (uint2*)(gxl + row * 132 + seg * 32);
#pragma unroll
      for (int q = 0; q < 4; ++q) {
        uint4 v = gsrc[q];
        uint2 a0 = {v.x, v.y}, a1 = {v.z, v.w};
        dst[q * 2] = a0;
        dst[q * 2 + 1] = a1;
      }
    }
  }
  const int j = tid;
  const float bsum = b_ih[j] + b_hh[j];
#if HAVE_FDOT2
  h16x2 wreg[64];
#pragma unroll
  for (int kk = 0; kk < 64; ++kk) {
    union { uint32_t u; h16x2 h; } cv; cv.u = whhp[kk * 512 + j];
    wreg[kk] = cv.h;
  }
#else
  float wreg[128];
#pragma unroll
  for (int kk = 0; kk < 64; ++kk) {
    union { uint32_t u; h16x2 h; } cv; cv.u = whhp[kk * 512 + j];
    wreg[kk * 2] = (float)cv.h.x;
    wreg[kk * 2 + 1] = (float)cv.h.y;
  }
#endif
  if (tid < Hn) { h2l[tid] = (_Float16)0.f; h32[tid] = 0.f; }
  float c_st = 0.f;
  __syncthreads();

  float* outp = out + (size_t)b * Tn * Hn;
  for (int t = 0; t < Tn; ++t) {
    const _Float16 gxv = *(const _Float16*)&gxl[j * 132 + t];
    float a0 = 0.f, a1 = 0.f, a2 = 0.f, a3 = 0.f;
#if HAVE_FDOT2
    const h16x2* hc = (const h16x2*)h2l;
#pragma unroll
    for (int kk = 0; kk < 16; ++kk) {
      a0 = __builtin_amdgcn_fdot2(wreg[kk * 4 + 0], hc[kk * 4 + 0], a0, false);
      a1 = __builtin_amdgcn_fdot2(wreg[kk * 4 + 1], hc[kk * 4 + 1], a1, false);
      a2 = __builtin_amdgcn_fdot2(wreg[kk * 4 + 2], hc[kk * 4 + 2], a2, false);
      a3 = __builtin_amdgcn_fdot2(wreg[kk * 4 + 3], hc[kk * 4 + 3], a3, false);
    }
#else
#pragma unroll
    for (int kk = 0; kk < 32; ++kk) {
      a0 = fmaf(wreg[kk * 4 + 0], h32[kk * 4 + 0], a0);
      a1 = fmaf(wreg[kk * 4 + 1], h32[kk * 4 + 1], a1);
      a2 = fmaf(wreg[kk * 4 + 2], h32[kk * 4 + 2], a2);
      a3 = fmaf(wreg[kk * 4 + 3], h32[kk * 4 + 3], a3);
    }
#endif
    gstep[j] = (a0 + a1) + (a2 + a3) + bsum + (float)gxv;
    __syncthreads();
    // replicated activation: every thread computes its d = tid&127 lane
    const int d = tid & 127;
    const float gi = gstep[d];
    const float gf = gstep[Hn + d];
    const float gg = gstep[2 * Hn + d];
    const float go = gstep[3 * Hn + d];
    c_st = sigm(gf) * c_st + sigm(gi) * tanh_fast(gg);
    const float hnew = sigm(go) * tanh_fast(c_st);
    if (tid < Hn) {
      outp[t * Hn + d] = hnew;
      h2l[d] = (_Float16)hnew;
      h32[d] = hnew;
    }
    __syncthreads();
  }
}

// ---------------------------------------------------------------------------
extern "C" void kernel_launch(void* const* d_in, const int* in_sizes, int n_in,
                              void* d_out, int out_size, void* d_ws, size_t ws_size,
                              hipStream_t stream) {
  (void)in_sizes; (void)n_in; (void)out_size; (void)ws_size;
  const float* input = (const float*)d_in[0];
  const float* w_attn = (const float*)d_in[1];
  // d_in[2] = b_attn: dead (softmax shift-invariance), as are w_h, w_c.
  const float* W_ih = (const float*)d_in[3];
  const float* W_hh = (const float*)d_in[4];
  const float* b_ih = (const float*)d_in[5];
  const float* b_hh = (const float*)d_in[6];
  float* out = (float*)d_out;

  char* ws = (char*)d_ws;
  float* ex = (float*)ws;                                   // 131072 B
  unsigned short* whi = (unsigned short*)(ws + 131072);      // 1 MB
  unsigned short* wlo = (unsigned short*)(ws + 1179648);     // 1 MB
  uint32_t* whhp = (uint32_t*)(ws + 2228224);                // 131072 B
  unsigned short* gxw = (unsigned short*)(ws + 2359296);     // 33.5 MB

  k_ex<<<8192, 256, 0, stream>>>(input, w_attn, ex);
  k_prep_wih<<<256, 256, 0, stream>>>(W_ih, whi, wlo);
  k_prep_whh<<<128, 256, 0, stream>>>(W_hh, whhp);
  k_gates<<<1024, 256, 0, stream>>>(input, ex, whi, wlo, gxw);
  k_rec<<<Bn, 512, 0, stream>>>(gxw, whhp, b_ih, b_hh, out);
}

// Round 5
// 377.614 us; speedup vs baseline: 1.1510x; 1.1510x over previous
//
#include <hip/hip_runtime.h>
#include <cstdint>
#include <cstddef>

// Problem dims (B, D, F, T, H) = (256, 128, 8, 128, 128)
#define Bn 256
#define Dn 128
#define Fn 8
#define Tn 128
#define Hn 128
#define Kn 1024   // D*F
#define Mn 512    // 4*H

typedef float f32x4 __attribute__((ext_vector_type(4)));
typedef short s16x8 __attribute__((ext_vector_type(8)));
typedef _Float16 h16x2 __attribute__((ext_vector_type(2)));
typedef _Float16 h16x8 __attribute__((ext_vector_type(8)));

#if defined(__has_builtin)
#if __has_builtin(__builtin_amdgcn_fdot2)
#define HAVE_FDOT2 1
#else
#define HAVE_FDOT2 0
#endif
#if __has_builtin(__builtin_amdgcn_cvt_pk_bf16_f32)
#define HAVE_PK_BF16 1
#else
#define HAVE_PK_BF16 0
#endif
#else
#define HAVE_FDOT2 0
#define HAVE_PK_BF16 0
#endif

__device__ __forceinline__ unsigned short f32_to_bf16_rne(float f) {
  union { float f; uint32_t u; } v; v.f = f;
  uint32_t u = v.u;
  u += 0x7fffu + ((u >> 16) & 1u);
  return (unsigned short)(u >> 16);
}
__device__ __forceinline__ uint32_t pack2_bf16(float a, float b) {
#if HAVE_PK_BF16
  typedef __bf16 bf16x2_t __attribute__((ext_vector_type(2)));
  union { bf16x2_t v; uint32_t u; } cv;
  cv.v = __builtin_amdgcn_cvt_pk_bf16_f32(a, b);
  return cv.u;
#else
  return (uint32_t)f32_to_bf16_rne(a) | ((uint32_t)f32_to_bf16_rne(b) << 16);
#endif
}
__device__ __forceinline__ float sigm(float x) { return 1.0f / (1.0f + __expf(-x)); }
__device__ __forceinline__ float tanh_fast(float x) { return 1.0f - 2.0f / (__expf(2.0f * x) + 1.0f); }

// ---------------------------------------------------------------------------
// K1: ex[b,d] = input[b,d,:,:] . w_x   (one wave per (b,d))
// softmax shift-invariance kills the h/c/b_attn term entirely.
// ---------------------------------------------------------------------------
__global__ __launch_bounds__(256) void k_ex(const float* __restrict__ input,
                                            const float* __restrict__ w_attn,
                                            float* __restrict__ ex) {
  __shared__ float wx[Kn];
  const int tid = threadIdx.x;
  ((float4*)wx)[tid] = ((const float4*)(w_attn + 2 * Hn))[tid];
  __syncthreads();
  const int w = tid >> 6, lane = tid & 63;
  const int gid = blockIdx.x * 4 + w;  // b*128 + d
  const float4* xp = (const float4*)(input + (size_t)gid * Kn);
  const float4* wx4 = (const float4*)wx;
  float acc = 0.f;
#pragma unroll
  for (int r = 0; r < 4; ++r) {
    float4 x = xp[lane + r * 64];
    float4 ww = wx4[lane + r * 64];
    acc += x.x * ww.x + x.y * ww.y + x.z * ww.z + x.w * ww.w;
  }
#pragma unroll
  for (int off = 32; off; off >>= 1) acc += __shfl_xor(acc, off);
  if (lane == 0) ex[gid] = acc;
}

// ---------------------------------------------------------------------------
// K2 (merged prep):
//  blocks 0..255 : W_ih -> hi/lo bf16 MFMA A-frags
//  blocks 256..383: W_hh -> packed f16 pairs transposed (whhp[kk*512+j])
// ---------------------------------------------------------------------------
__global__ __launch_bounds__(256) void k_prep(const float* __restrict__ W_ih,
                                              const float* __restrict__ W_hh,
                                              unsigned short* __restrict__ whi,
                                              unsigned short* __restrict__ wlo,
                                              uint32_t* __restrict__ whhp) {
  const int bid = blockIdx.x;
  const int tid = threadIdx.x;
  if (bid < 256) {
    const int gid = bid * 256 + tid;  // 65536 groups of 8
    const int lane = gid & 63;
    const int kt = (gid >> 6) & 31;
    const int mt = gid >> 11;
    const int row = mt * 16 + (lane & 15);
    const int col = kt * 32 + (lane >> 4) * 8;
    const float* src = W_ih + row * Kn + col;
    unsigned short hi8[8], lo8[8];
#pragma unroll
    for (int j = 0; j < 8; ++j) {
      float wv = src[j];
      unsigned short h = f32_to_bf16_rne(wv);
      hi8[j] = h;
      union { uint32_t u; float f; } hb; hb.u = ((uint32_t)h) << 16;
      lo8[j] = f32_to_bf16_rne(wv - hb.f);
    }
    uint4 ph, pl;
    ph.x = (uint32_t)hi8[0] | ((uint32_t)hi8[1] << 16);
    ph.y = (uint32_t)hi8[2] | ((uint32_t)hi8[3] << 16);
    ph.z = (uint32_t)hi8[4] | ((uint32_t)hi8[5] << 16);
    ph.w = (uint32_t)hi8[6] | ((uint32_t)hi8[7] << 16);
    pl.x = (uint32_t)lo8[0] | ((uint32_t)lo8[1] << 16);
    pl.y = (uint32_t)lo8[2] | ((uint32_t)lo8[3] << 16);
    pl.z = (uint32_t)lo8[4] | ((uint32_t)lo8[5] << 16);
    pl.w = (uint32_t)lo8[6] | ((uint32_t)lo8[7] << 16);
    ((uint4*)whi)[gid] = ph;
    ((uint4*)wlo)[gid] = pl;
  } else {
    const int g = (bid - 256) * 256 + tid;  // 32768
    const int j = g & 511, kk = g >> 9;
    float2 wv = ((const float2*)(W_hh + (size_t)j * Hn))[kk];
    h16x2 t2; t2.x = (_Float16)wv.x; t2.y = (_Float16)wv.y;
    union { h16x2 h; uint32_t u; } cv; cv.h = t2;
    whhp[kk * 512 + j] = cv.u;
  }
}

// ---------------------------------------------------------------------------
// K3: gates GEMM. grid = 1024: b = (bid&7)|((bid>>5)<<3), p = (bid>>3)&3 so
// the 4 panels of one b share an XCD (bids differ by 8/16/24) and co-reside
// -> input[b] fetched ~once per XCD. 256 thr. Conflict-free staging layout
// [kb][t][8k] with lane-contiguous ds_write_b128. Register double-buffer for
// W frags + x prefetch; one barrier per K-tile.
// ---------------------------------------------------------------------------
__global__ __launch_bounds__(256, 2) void k_gates(
    const float* __restrict__ input, const float* __restrict__ ex,
    const unsigned short* __restrict__ whi, const unsigned short* __restrict__ wlo,
    unsigned short* __restrict__ gx) {
  __shared__ __align__(16) unsigned char smem[34816];
  __shared__ float a_lds[Dn];
  __shared__ float sred[8];
  unsigned short* buf0 = (unsigned short*)smem;
  unsigned short* buf1 = buf0 + 8192;
  _Float16* lds_out = (_Float16*)smem;

  const int tid = threadIdx.x;
  const int bid = blockIdx.x;
  const int p = (bid >> 3) & 3;
  const int b = (bid & 7) | ((bid >> 5) << 3);
  const int w = tid >> 6;
  const int lane = tid & 63;
  const int quad = lane >> 4;
  const int l15 = lane & 15;

  // ---- in-block softmax over ex[b,:] -> a_lds ----
  float v = (tid < Dn) ? ex[b * Dn + tid] : -3.4e38f;
  float m = v;
#pragma unroll
  for (int off = 32; off; off >>= 1) m = fmaxf(m, __shfl_xor(m, off));
  if (lane == 0) sred[w] = m;
  __syncthreads();
  m = fmaxf(fmaxf(sred[0], sred[1]), fmaxf(sred[2], sred[3]));
  float e = (tid < Dn) ? __expf(v - m) : 0.f;
  float s = e;
#pragma unroll
  for (int off = 32; off; off >>= 1) s += __shfl_xor(s, off);
  if (lane == 0) sred[4 + w] = s;
  __syncthreads();
  s = sred[4] + sred[5] + sred[6] + sred[7];
  if (tid < Dn) a_lds[tid] = e / s;

  f32x4 acc[2][8];
#pragma unroll
  for (int i = 0; i < 2; ++i)
#pragma unroll
    for (int j = 0; j < 8; ++j) { f32x4 z = {0.f, 0.f, 0.f, 0.f}; acc[i][j] = z; }

  const float* xb = input + (size_t)b * Kn * Tn;
  const int mtg0 = p * 8 + w * 2;

  // W fragment register double-buffer: idx = mt*4 + kf*2 + (0=hi,1=lo)
  s16x8 wcur[8], wnxt[8];
#pragma unroll
  for (int mt = 0; mt < 2; ++mt)
#pragma unroll
    for (int kf = 0; kf < 2; ++kf) {
      const size_t fo = (((size_t)(mtg0 + mt) * 32 + kf) * 64 + lane) * 8;
      wcur[mt * 4 + kf * 2 + 0] = *(const s16x8*)(whi + fo);
      wcur[mt * 4 + kf * 2 + 1] = *(const s16x8*)(wlo + fo);
    }

  __syncthreads();  // a_lds ready

  // ---- stage tile 0 ----
  float xr[2][2][8];
#pragma unroll
  for (int ck = 0; ck < 2; ++ck)
#pragma unroll
    for (int ct = 0; ct < 2; ++ct) {
      const int kb = 2 * w + ck;
      const float* col = xb + (size_t)(kb * 8) * Tn + lane + 64 * ct;
#pragma unroll
      for (int j = 0; j < 8; ++j) xr[ck][ct][j] = col[(size_t)j * Tn];
    }
#pragma unroll
  for (int ck = 0; ck < 2; ++ck) {
    const int kb = 2 * w + ck;
    const float av = a_lds[kb];
#pragma unroll
    for (int ct = 0; ct < 2; ++ct) {
      const int tt = lane + 64 * ct;
      uint4 pk;
      pk.x = pack2_bf16(av * xr[ck][ct][0], av * xr[ck][ct][1]);
      pk.y = pack2_bf16(av * xr[ck][ct][2], av * xr[ck][ct][3]);
      pk.z = pack2_bf16(av * xr[ck][ct][4], av * xr[ck][ct][5]);
      pk.w = pack2_bf16(av * xr[ck][ct][6], av * xr[ck][ct][7]);
      *(uint4*)(buf0 + (size_t)(kb * 128 + tt) * 8) = pk;
    }
  }
  __syncthreads();

  for (int kt = 0; kt < 16; ++kt) {
    unsigned short* cur = (kt & 1) ? buf1 : buf0;
    unsigned short* nxt = (kt & 1) ? buf0 : buf1;
    // ---- prefetch next x tile + next W frags (consumed after MFMA) ----
    if (kt < 15) {
      const int k0n = (kt + 1) * 64;
#pragma unroll
      for (int ck = 0; ck < 2; ++ck)
#pragma unroll
        for (int ct = 0; ct < 2; ++ct) {
          const int kb = 2 * w + ck;
          const float* col = xb + (size_t)(k0n + kb * 8) * Tn + lane + 64 * ct;
#pragma unroll
          for (int j = 0; j < 8; ++j) xr[ck][ct][j] = col[(size_t)j * Tn];
        }
#pragma unroll
      for (int mt = 0; mt < 2; ++mt)
#pragma unroll
        for (int kf = 0; kf < 2; ++kf) {
          const size_t fo = (((size_t)(mtg0 + mt) * 32 + (kt + 1) * 2 + kf) * 64 + lane) * 8;
          wnxt[mt * 4 + kf * 2 + 0] = *(const s16x8*)(whi + fo);
          wnxt[mt * 4 + kf * 2 + 1] = *(const s16x8*)(wlo + fo);
        }
    }
    // ---- MFMA on current tile ----
#pragma unroll
    for (int kf = 0; kf < 2; ++kf) {
      s16x8 bfr[8];
      const int kbr = kf * 4 + quad;
#pragma unroll
      for (int nt = 0; nt < 8; ++nt)
        bfr[nt] = *(const s16x8*)(cur + (size_t)(kbr * 128 + nt * 16 + l15) * 8);
#pragma unroll
      for (int mt = 0; mt < 2; ++mt)
#pragma unroll
        for (int nt = 0; nt < 8; ++nt) {
          acc[mt][nt] = __builtin_amdgcn_mfma_f32_16x16x32_bf16(wcur[mt * 4 + kf * 2 + 0], bfr[nt], acc[mt][nt], 0, 0, 0);
          acc[mt][nt] = __builtin_amdgcn_mfma_f32_16x16x32_bf16(wcur[mt * 4 + kf * 2 + 1], bfr[nt], acc[mt][nt], 0, 0, 0);
        }
    }
    // ---- convert prefetched tile into other buffer; rotate W regs ----
    if (kt < 15) {
#pragma unroll
      for (int ck = 0; ck < 2; ++ck) {
        const int kb = 2 * w + ck;
        const float av = a_lds[(kt + 1) * 8 + kb];
#pragma unroll
        for (int ct = 0; ct < 2; ++ct) {
          const int tt = lane + 64 * ct;
          uint4 pk;
          pk.x = pack2_bf16(av * xr[ck][ct][0], av * xr[ck][ct][1]);
          pk.y = pack2_bf16(av * xr[ck][ct][2], av * xr[ck][ct][3]);
          pk.z = pack2_bf16(av * xr[ck][ct][4], av * xr[ck][ct][5]);
          pk.w = pack2_bf16(av * xr[ck][ct][6], av * xr[ck][ct][7]);
          *(uint4*)(nxt + (size_t)(kb * 128 + tt) * 8) = pk;
        }
      }
#pragma unroll
      for (int i = 0; i < 8; ++i) wcur[i] = wnxt[i];
    }
    __syncthreads();
  }

  // ---- epilogue: acc -> LDS bounce (pitch 136) -> coalesced global f16 ----
#pragma unroll
  for (int mt = 0; mt < 2; ++mt)
#pragma unroll
    for (int nt = 0; nt < 8; ++nt)
#pragma unroll
      for (int r = 0; r < 4; ++r) {
        const int jl = (w * 2 + mt) * 16 + quad * 4 + r;  // 0..127
        lds_out[jl * 136 + nt * 16 + l15] = (_Float16)acc[mt][nt][r];
      }
  __syncthreads();
  {
    const int jr = tid >> 1, half = tid & 1;
    const uint4* lsrc = (const uint4*)(lds_out + jr * 136 + half * 64);
    uint4* gdst = (uint4*)(gx + ((size_t)(b * Mn + p * 128 + jr)) * Tn + half * 64);
#pragma unroll
    for (int i = 0; i < 8; ++i) gdst[i] = lsrc[i];
  }
}

// ---------------------------------------------------------------------------
// K4: LSTM recurrence. 256 blocks (1/batch) x 256 thr (2 rows each).
// h read as 16x ds_read_b128 broadcast per thread per step; gx LDS pitch 130
// (conflict-free u16 reads). W_hh rows in VGPRs as f16 pairs; fdot2.
// ---------------------------------------------------------------------------
__global__ __launch_bounds__(256) void k_rec(
    const unsigned short* __restrict__ gx, const uint32_t* __restrict__ whhp,
    const float* __restrict__ b_ih, const float* __restrict__ b_hh,
    float* __restrict__ out) {
  __shared__ unsigned short gxl[512 * 130];  // 133120 B
  __shared__ float gstep[Mn];
  __shared__ __align__(16) _Float16 h2l[Hn];

  const int tid = threadIdx.x;
  const int b = blockIdx.x;

  // ---- preload gx[b] (128 KB) into LDS, pitch 130 ----
  // each row = 128 u16 = 256 B = 16 chunks of 16 B  (R4 bug: used 8/row)
  {
    const uint4* src = (const uint4*)(gx + (size_t)b * Mn * Tn);
#pragma unroll
    for (int it = 0; it < 32; ++it) {
      const int c = it * 256 + tid;     // 16B chunk id, 0..8191
      const int row = c >> 4, off = c & 15;
      uint4 vv = src[c];
      uint32_t* dst = (uint32_t*)((char*)gxl + (size_t)row * 260 + off * 16);
      dst[0] = vv.x; dst[1] = vv.y; dst[2] = vv.z; dst[3] = vv.w;
    }
  }
  const int j0 = tid, j1 = tid + 256;
  const float bs0 = b_ih[j0] + b_hh[j0];
  const float bs1 = b_ih[j1] + b_hh[j1];
  h16x2 wr0[64], wr1[64];
#pragma unroll
  for (int kk = 0; kk < 64; ++kk) {
    union { uint32_t u; h16x2 h; } c0, c1;
    c0.u = whhp[kk * 512 + j0];
    c1.u = whhp[kk * 512 + j1];
    wr0[kk] = c0.h; wr1[kk] = c1.h;
  }
  if (tid < Hn) h2l[tid] = (_Float16)0.f;
  float c_st = 0.f;
  __syncthreads();

  float* outp = out + (size_t)b * Tn * Hn;
  for (int t = 0; t < Tn; ++t) {
    float g0 = bs0 + (float)(*(const _Float16*)&gxl[j0 * 130 + t]);
    float g1 = bs1 + (float)(*(const _Float16*)&gxl[j1 * 130 + t]);
    float a0 = 0.f, a1 = 0.f, a2 = 0.f, a3 = 0.f;
    float d0 = 0.f, d1 = 0.f, d2 = 0.f, d3 = 0.f;
    const h16x8* hv = (const h16x8*)h2l;
#pragma unroll
    for (int q = 0; q < 16; ++q) {
      union { h16x8 v; h16x2 pr[4]; } u; u.v = hv[q];  // ds_read_b128 broadcast
#if HAVE_FDOT2
      a0 = __builtin_amdgcn_fdot2(wr0[q * 4 + 0], u.pr[0], a0, false);
      a1 = __builtin_amdgcn_fdot2(wr0[q * 4 + 1], u.pr[1], a1, false);
      a2 = __builtin_amdgcn_fdot2(wr0[q * 4 + 2], u.pr[2], a2, false);
      a3 = __builtin_amdgcn_fdot2(wr0[q * 4 + 3], u.pr[3], a3, false);
      d0 = __builtin_amdgcn_fdot2(wr1[q * 4 + 0], u.pr[0], d0, false);
      d1 = __builtin_amdgcn_fdot2(wr1[q * 4 + 1], u.pr[1], d1, false);
      d2 = __builtin_amdgcn_fdot2(wr1[q * 4 + 2], u.pr[2], d2, false);
      d3 = __builtin_amdgcn_fdot2(wr1[q * 4 + 3], u.pr[3], d3, false);
#else
#pragma unroll
      for (int z = 0; z < 4; ++z) {
        a0 += (float)wr0[q * 4 + z].x * (float)u.pr[z].x + (float)wr0[q * 4 + z].y * (float)u.pr[z].y;
        d0 += (float)wr1[q * 4 + z].x * (float)u.pr[z].x + (float)wr1[q * 4 + z].y * (float)u.pr[z].y;
      }
#endif
    }
    gstep[j0] = (a0 + a1) + (a2 + a3) + g0;
    gstep[j1] = (d0 + d1) + (d2 + d3) + g1;
    __syncthreads();
    const int d = tid & 127;
    const float gi = gstep[d];
    const float gf = gstep[Hn + d];
    const float gg = gstep[2 * Hn + d];
    const float go = gstep[3 * Hn + d];
    c_st = sigm(gf) * c_st + sigm(gi) * tanh_fast(gg);
    const float hnew = sigm(go) * tanh_fast(c_st);
    if (tid < Hn) {
      outp[t * Hn + d] = hnew;
      h2l[d] = (_Float16)hnew;
    }
    __syncthreads();
  }
}

// ---------------------------------------------------------------------------
extern "C" void kernel_launch(void* const* d_in, const int* in_sizes, int n_in,
                              void* d_out, int out_size, void* d_ws, size_t ws_size,
                              hipStream_t stream) {
  (void)in_sizes; (void)n_in; (void)out_size; (void)ws_size;
  const float* input = (const float*)d_in[0];
  const float* w_attn = (const float*)d_in[1];
  // d_in[2] = b_attn: dead (softmax shift-invariance), as are w_h, w_c.
  const float* W_ih = (const float*)d_in[3];
  const float* W_hh = (const float*)d_in[4];
  const float* b_ih = (const float*)d_in[5];
  const float* b_hh = (const float*)d_in[6];
  float* out = (float*)d_out;

  char* ws = (char*)d_ws;
  float* ex = (float*)ws;                                   // 131072 B
  unsigned short* whi = (unsigned short*)(ws + 131072);      // 1 MB
  unsigned short* wlo = (unsigned short*)(ws + 1179648);     // 1 MB
  uint32_t* whhp = (uint32_t*)(ws + 2228224);                // 131072 B
  unsigned short* gxw = (unsigned short*)(ws + 2359296);     // 33.5 MB

  k_ex<<<8192, 256, 0, stream>>>(input, w_attn, ex);
  k_prep<<<384, 256, 0, stream>>>(W_ih, W_hh, whi, wlo, whhp);
  k_gates<<<1024, 256, 0, stream>>>(input, ex, whi, wlo, gxw);
  k_rec<<<Bn, 256, 0, stream>>>(gxw, whhp, b_ih, b_hh, out);
}